// Round 6
// baseline (284.768 us; speedup 1.0000x reference)
//
#include <hip/hip_runtime.h>
#include <hip/hip_bf16.h>
#include <stdint.h>

#define T      3072
#define CH     64
#define HEADS  32
#define BM     128
#define BN     64
#define NIT    (T / BN)
#define PSTR   72     // P row stride (u16): 144 B, 16B-aligned b128 reads, bank-balanced

typedef unsigned short u16;
typedef short short8 __attribute__((ext_vector_type(8)));   // 8 bf16 as i16
typedef float floatx4 __attribute__((ext_vector_type(4)));

#define QSCALE 0.18033688011112042f   // (1/8) * log2(e)
#define KSWZ(r) ((((r) + 2 * ((r) >> 3))) & 7)

__device__ __forceinline__ unsigned pk2(float a, float b) {  // 2 fp32 -> packed bf16x2 (RNE)
  union { __hip_bfloat162 h; unsigned u; } cv;
  cv.h = __float22bfloat162_rn(float2{a, b});
  return cv.u;
}

// ---------- prepass: z=0 K transpose (ch,t)->(t,ch) bf16 ; z=1 V flat cast ----------
// grid (48, 32, 2), 256 threads
__global__ __launch_bounds__(256) void prep(
    const float* __restrict__ qkv, u16* __restrict__ Kt, u16* __restrict__ Vo) {
  const int tid = threadIdx.x;

  if (blockIdx.z == 1) {                 // V: flat cast (layout identical), 16 elems/thread
    const int fb = blockIdx.x + 48 * blockIdx.y;        // 0..1535
    const int b = fb / 384, rem = fb - b * 384;
    const size_t g = (size_t)rem * 4096 + tid * 16;
    const float* src = qkv + (size_t)b * 1536 * T + (size_t)1024 * T + g;
    uint4 o[2];
#pragma unroll
    for (int h = 0; h < 2; ++h) {
      float4 a = *(const float4*)(src + h * 8);
      float4 c = *(const float4*)(src + h * 8 + 4);
      o[h].x = pk2(a.x, a.y); o[h].y = pk2(a.z, a.w);
      o[h].z = pk2(c.x, c.y); o[h].w = pk2(c.z, c.w);
    }
    uint4* d = (uint4*)(Vo + (size_t)b * 512 * T + g);
    d[0] = o[0]; d[1] = o[1];
    return;
  }

  // K transpose
  __shared__ u16 tl[64][66];             // stride 33 dw: 2-way-free writes & reads
  const int ttile = blockIdx.x, hh = blockIdx.y;
  const int b = hh >> 3, h = hh & 7;
  const int t0 = ttile * 64;
  const float* src = qkv + (size_t)(b * 1536 + 512 + h * CH) * T;

#pragma unroll
  for (int p = 0; p < 2; ++p) {
    const int c0 = p * 32 + ((tid >> 4) << 1);
    const int ts = (tid & 15) * 4;
    float4 a = *(const float4*)(src + (size_t)c0 * T + t0 + ts);
    float4 c = *(const float4*)(src + (size_t)(c0 + 1) * T + t0 + ts);
    *(unsigned*)&tl[ts + 0][c0] = pk2(a.x, c.x);
    *(unsigned*)&tl[ts + 1][c0] = pk2(a.y, c.y);
    *(unsigned*)&tl[ts + 2][c0] = pk2(a.z, c.z);
    *(unsigned*)&tl[ts + 3][c0] = pk2(a.w, c.w);
  }
  __syncthreads();
  u16* dst = Kt + (size_t)hh * T * CH;
#pragma unroll
  for (int q = 0; q < 2; ++q) {
    const int t = q * 32 + (tid >> 3);
    const int cc = (tid & 7) * 8;
    uint4 v;
    v.x = *(const unsigned*)&tl[t][cc + 0];
    v.y = *(const unsigned*)&tl[t][cc + 2];
    v.z = *(const unsigned*)&tl[t][cc + 4];
    v.w = *(const unsigned*)&tl[t][cc + 6];
    *(uint4*)(dst + (size_t)(t0 + t) * CH + cc) = v;
  }
}

// ---------- flash attention v6: explicit reg-carried staging, 1 barrier/iter ----------
// grid (24 q-tiles, 32 heads), 256 threads = 4 waves; 51200 B LDS -> 3 blocks/CU
__global__ __launch_bounds__(256, 3) void attn(
    const float* __restrict__ qkv, const u16* __restrict__ Kt,
    const u16* __restrict__ Vg, float* __restrict__ out) {
  __shared__ __align__(16) u16 KB[2][BN * CH];    // [s][c], xor-swizzled 16B blocks
  __shared__ __align__(16) u16 VB[2][CH * BN];    // [c][s], xor-swizzled
  __shared__ __align__(16) u16 PL[4][32 * PSTR];  // per-wave [t][s]

  const int qtile = blockIdx.x, hh = blockIdx.y;
  const int tid = threadIdx.x;
  const int wave = tid >> 6, lane = tid & 63;
  const int l15 = lane & 15, quad = lane >> 4;
  const int t0 = qtile * BM + wave * 32;
  const int b = hh >> 3, h = hh & 7;

  const u16* Kh = Kt + (size_t)hh * T * CH;
  const u16* Vh = Vg + (size_t)hh * CH * T;

  // ---- Q prologue: direct strided fp32 loads -> scaled bf16 B-frags ----
  const float* qsrc = qkv + (size_t)(b * 1536 + h * CH) * T;
  short8 qf[2][2];
#pragma unroll
  for (int tq = 0; tq < 2; ++tq)
#pragma unroll
    for (int kc = 0; kc < 2; ++kc) {
      const int t = t0 + tq * 16 + l15;
      unsigned w[4];
#pragma unroll
      for (int j = 0; j < 4; ++j) {
        const int c = kc * 32 + quad * 8 + 2 * j;
        float a = qsrc[(size_t)c * T + t] * QSCALE;
        float d = qsrc[(size_t)(c + 1) * T + t] * QSCALE;
        w[j] = pk2(a, d);
      }
      qf[tq][kc] = *(const short8*)&w[0];
    }

  floatx4 oacc[2][4] = {};
  float lsum[2] = {0.f, 0.f};

  // staging geometry: tile = 64 rows x 8 16B-blocks; thread covers (row, blk) twice
  const int sblk = tid & 7;
  int srow[2], sphys[2];
#pragma unroll
  for (int j = 0; j < 2; ++j) {
    srow[j]  = j * 32 + (tid >> 3);
    sphys[j] = sblk ^ KSWZ(srow[j]);
  }
  const int swl = KSWZ(l15);
  u16* plw = PL[wave];

  uint4 kr[2], vr[2];
#pragma unroll
  for (int j = 0; j < 2; ++j) {           // tile 0 loads
    kr[j] = *(const uint4*)(Kh + (size_t)srow[j] * CH + sblk * 8);
    vr[j] = *(const uint4*)(Vh + (size_t)srow[j] * T + sblk * 8);
  }

  for (int it = 0; it < NIT; ++it) {
    const int cur = it & 1;
    u16* kb = (u16*)KB[cur];
    u16* vb = (u16*)VB[cur];

    // write staged tile (regs) -> LDS[cur]  (vmcnt wait on kr/vr happens here)
#pragma unroll
    for (int j = 0; j < 2; ++j) {
      *(uint4*)(kb + (srow[j] * 8 + sphys[j]) * 8) = kr[j];
      *(uint4*)(vb + (srow[j] * 8 + sphys[j]) * 8) = vr[j];
    }
    __syncthreads();                      // LDS[cur] visible; no vmem outstanding

    if (it + 1 < NIT) {                   // issue next-tile loads; consumed next iter
      const int s0n = (it + 1) * BN;
#pragma unroll
      for (int j = 0; j < 2; ++j) {
        kr[j] = *(const uint4*)(Kh + (size_t)(s0n + srow[j]) * CH + sblk * 8);
        vr[j] = *(const uint4*)(Vh + (size_t)srow[j] * T + s0n + sblk * 8);
      }
    }

    // S^T = K Q^T : A = K frag (LDS, swizzled), B = Q regs.
    // sacc[tq][nt][r] = S[t = l15+16tq][s = nt*16 + quad*4 + r]
    floatx4 sacc[2][4];
#pragma unroll
    for (int nt = 0; nt < 4; ++nt) {
      const int ph0 = quad ^ swl ^ ((nt & 1) * 4);
      const int base = (nt * 16 + l15) * CH;
      const short8 kf0 = *(const short8*)(kb + base + ph0 * 8);
      const short8 kf1 = *(const short8*)(kb + base + (ph0 ^ 4) * 8);
#pragma unroll
      for (int tq = 0; tq < 2; ++tq) {
        floatx4 z = {0.f, 0.f, 0.f, 0.f};
        z = __builtin_amdgcn_mfma_f32_16x16x32_bf16(kf0, qf[tq][0], z, 0, 0, 0);
        z = __builtin_amdgcn_mfma_f32_16x16x32_bf16(kf1, qf[tq][1], z, 0, 0, 0);
        sacc[tq][nt] = z;
      }
    }

    // static softmax (scale+log2e folded into Q): packed b64 P writes
#pragma unroll
    for (int tq = 0; tq < 2; ++tq)
#pragma unroll
      for (int nt = 0; nt < 4; ++nt) {
        floatx4 sv = sacc[tq][nt];
        float p0 = __builtin_amdgcn_exp2f(sv[0]);
        float p1 = __builtin_amdgcn_exp2f(sv[1]);
        float p2 = __builtin_amdgcn_exp2f(sv[2]);
        float p3 = __builtin_amdgcn_exp2f(sv[3]);
        lsum[tq] += (p0 + p1) + (p2 + p3);
        uint2 w; w.x = pk2(p0, p1); w.y = pk2(p2, p3);
        *(uint2*)(plw + (l15 + tq * 16) * PSTR + nt * 16 + quad * 4) = w;
      }

    // O = P V^T : A = P [t][s] (wave-local LDS), B = V^T (V [c][s] LDS, swizzled)
#pragma unroll
    for (int ks = 0; ks < 2; ++ks) {
      short8 pf0 = *(const short8*)(plw + l15 * PSTR + ks * 32 + quad * 8);
      short8 pf1 = *(const short8*)(plw + (l15 + 16) * PSTR + ks * 32 + quad * 8);
#pragma unroll
      for (int mt = 0; mt < 4; ++mt) {
        const int ph = quad ^ swl ^ ((mt & 1) * 4) ^ (ks * 4);
        const short8 vf = *(const short8*)(vb + (mt * 16 + l15) * BN + ph * 8);
        oacc[0][mt] = __builtin_amdgcn_mfma_f32_16x16x32_bf16(pf0, vf, oacc[0][mt], 0, 0, 0);
        oacc[1][mt] = __builtin_amdgcn_mfma_f32_16x16x32_bf16(pf1, vf, oacc[1][mt], 0, 0, 0);
      }
    }
  }

  // epilogue: full row sums (reduce across quads), then per-output-row linv via shfl
  float ls[2];
#pragma unroll
  for (int tq = 0; tq < 2; ++tq) {
    float s = lsum[tq];
    s += __shfl_xor(s, 16, 64);
    s += __shfl_xor(s, 32, 64);
    ls[tq] = s;                                        // sum for row l15 + 16tq
  }
  float linv[2][4];
#pragma unroll
  for (int tq = 0; tq < 2; ++tq)
#pragma unroll
    for (int r = 0; r < 4; ++r)
      linv[tq][r] = 1.0f / __shfl(ls[tq], quad * 4 + r, 64);

  // O rows t = t0 + tq*16 + quad*4 + r ; cols c = mt*16 + l15 ; float4 over r
#pragma unroll
  for (int tq = 0; tq < 2; ++tq) {
    const int tg = t0 + tq * 16 + quad * 4;
    const int band = tg >> 10, tt = tg & 1023;
    float* obase = out + (size_t)band * (4 * 512 * 1024)
                       + (size_t)b * (512 * 1024)
                       + (size_t)(h * CH) * 1024 + tt;
#pragma unroll
    for (int mt = 0; mt < 4; ++mt) {
      const int c = mt * 16 + l15;
      float4 v;
      v.x = oacc[tq][mt][0] * linv[tq][0];
      v.y = oacc[tq][mt][1] * linv[tq][1];
      v.z = oacc[tq][mt][2] * linv[tq][2];
      v.w = oacc[tq][mt][3] * linv[tq][3];
      *(float4*)(obase + (size_t)c * 1024) = v;
    }
  }
}

extern "C" void kernel_launch(void* const* d_in, const int* in_sizes, int n_in,
                              void* d_out, int out_size, void* d_ws, size_t ws_size,
                              hipStream_t stream) {
  (void)in_sizes; (void)n_in; (void)out_size; (void)ws_size;
  const float* qkv = (const float*)d_in[0];
  u16* Kt = (u16*)d_ws;                                 // 12.6 MB bf16
  u16* Vo = Kt + (size_t)HEADS * T * CH;                // 12.6 MB bf16
  float* out = (float*)d_out;

  prep<<<dim3(48, HEADS, 2), 256, 0, stream>>>(qkv, Kt, Vo);
  attn<<<dim3(T / BM, HEADS), 256, 0, stream>>>(qkv, Kt, Vo, out);
}

// Round 7
// 236.374 us; speedup vs baseline: 1.2047x; 1.2047x over previous
//
#include <hip/hip_runtime.h>
#include <hip/hip_bf16.h>
#include <stdint.h>

#define T      3072
#define CH     64
#define HEADS  32
#define BM     128    // q-rows per block (2 waves x 64 rows)
#define WROWS  64     // q-rows per wave (tq = 4)
#define BN     64
#define NIT    (T / BN)

typedef unsigned short u16;
typedef short short8 __attribute__((ext_vector_type(8)));   // 8 bf16 as i16
typedef float floatx4 __attribute__((ext_vector_type(4)));

#define QSCALE 0.18033688011112042f   // (1/8) * log2(e)
#define KSWZ(r) ((((r) + 2 * ((r) >> 3))) & 7)

__device__ __forceinline__ unsigned pk2(float a, float b) {  // 2 fp32 -> packed bf16x2 (RNE)
  union { __hip_bfloat162 h; unsigned u; } cv;
  cv.h = __float22bfloat162_rn(float2{a, b});
  return cv.u;
}

__device__ __forceinline__ void gl_lds16(const void* g, void* l) {
  __builtin_amdgcn_global_load_lds(
      (const __attribute__((address_space(1))) uint32_t*)g,
      (__attribute__((address_space(3))) uint32_t*)l, 16, 0, 0);
}

// ---------- prepass: z=0 K transpose (ch,t)->(t,ch) bf16 ; z=1 V flat cast ----------
// grid (48, 32, 2), 256 threads
__global__ __launch_bounds__(256) void prep(
    const float* __restrict__ qkv, u16* __restrict__ Kt, u16* __restrict__ Vo) {
  const int tid = threadIdx.x;

  if (blockIdx.z == 1) {                 // V: flat cast (layout identical), 16 elems/thread
    const int fb = blockIdx.x + 48 * blockIdx.y;        // 0..1535
    const int b = fb / 384, rem = fb - b * 384;
    const size_t g = (size_t)rem * 4096 + tid * 16;
    const float* src = qkv + (size_t)b * 1536 * T + (size_t)1024 * T + g;
    uint4 o[2];
#pragma unroll
    for (int h = 0; h < 2; ++h) {
      float4 a = *(const float4*)(src + h * 8);
      float4 c = *(const float4*)(src + h * 8 + 4);
      o[h].x = pk2(a.x, a.y); o[h].y = pk2(a.z, a.w);
      o[h].z = pk2(c.x, c.y); o[h].w = pk2(c.z, c.w);
    }
    uint4* d = (uint4*)(Vo + (size_t)b * 512 * T + g);
    d[0] = o[0]; d[1] = o[1];
    return;
  }

  // K transpose
  __shared__ u16 tl[64][66];             // stride 33 dw: 2-way-free writes & reads
  const int ttile = blockIdx.x, hh = blockIdx.y;
  const int b = hh >> 3, h = hh & 7;
  const int t0 = ttile * 64;
  const float* src = qkv + (size_t)(b * 1536 + 512 + h * CH) * T;

#pragma unroll
  for (int p = 0; p < 2; ++p) {
    const int c0 = p * 32 + ((tid >> 4) << 1);
    const int ts = (tid & 15) * 4;
    float4 a = *(const float4*)(src + (size_t)c0 * T + t0 + ts);
    float4 c = *(const float4*)(src + (size_t)(c0 + 1) * T + t0 + ts);
    *(unsigned*)&tl[ts + 0][c0] = pk2(a.x, c.x);
    *(unsigned*)&tl[ts + 1][c0] = pk2(a.y, c.y);
    *(unsigned*)&tl[ts + 2][c0] = pk2(a.z, c.z);
    *(unsigned*)&tl[ts + 3][c0] = pk2(a.w, c.w);
  }
  __syncthreads();
  u16* dst = Kt + (size_t)hh * T * CH;
#pragma unroll
  for (int q = 0; q < 2; ++q) {
    const int t = q * 32 + (tid >> 3);
    const int cc = (tid & 7) * 8;
    uint4 v;
    v.x = *(const unsigned*)&tl[t][cc + 0];
    v.y = *(const unsigned*)&tl[t][cc + 2];
    v.z = *(const unsigned*)&tl[t][cc + 4];
    v.w = *(const unsigned*)&tl[t][cc + 6];
    *(uint4*)(dst + (size_t)(t0 + t) * CH + cc) = v;
  }
}

// ---------- flash attention v7: 2 waves x 64 q-rows, DMA dbuf staging, 1 barrier/iter ----
// grid (24 q-tiles, 32 heads), 128 threads = 2 waves; 49152 B LDS -> 3 blocks/CU
__global__ __launch_bounds__(128, 2) void attn(
    const float* __restrict__ qkv, const u16* __restrict__ Kt,
    const u16* __restrict__ Vg, float* __restrict__ out) {
  __shared__ __align__(16) u16 KB[2][BN * CH];      // [s][c], xor-swizzled 16B blocks
  __shared__ __align__(16) u16 VB[2][CH * BN];      // [c][s], xor-swizzled
  __shared__ __align__(16) u16 PL[2][WROWS * BN];   // per-wave [t][s], stride 64, 8B-swizzled

  const int qtile = blockIdx.x, hh = blockIdx.y;
  const int tid = threadIdx.x;
  const int wave = tid >> 6, lane = tid & 63;
  const int l15 = lane & 15, quad = lane >> 4;
  const int t0w = qtile * BM + wave * WROWS;
  const int b = hh >> 3, h = hh & 7;

  const u16* Kh = Kt + (size_t)hh * T * CH;
  const u16* Vh = Vg + (size_t)hh * CH * T;

  // ---- Q prologue: direct strided fp32 loads -> scaled bf16 B-frags ----
  // qf[tq][kc] dword j holds c = kc*32 + quad*8 + 2j (+1), t = t0w + tq*16 + l15
  const float* qsrc = qkv + (size_t)(b * 1536 + h * CH) * T;
  short8 qf[4][2];
#pragma unroll
  for (int tq = 0; tq < 4; ++tq)
#pragma unroll
    for (int kc = 0; kc < 2; ++kc) {
      const int t = t0w + tq * 16 + l15;
      unsigned w[4];
#pragma unroll
      for (int j = 0; j < 4; ++j) {
        const int c = kc * 32 + quad * 8 + 2 * j;
        float a = qsrc[(size_t)c * T + t] * QSCALE;
        float d = qsrc[(size_t)(c + 1) * T + t] * QSCALE;
        w[j] = pk2(a, d);
      }
      qf[tq][kc] = *(const short8*)&w[0];
    }

  floatx4 oacc[4][4] = {};
  float lsum[4] = {0.f, 0.f, 0.f, 0.f};

  // staging: 512 16B-slots per tensor; 4 instr x 128 threads; swizzle cb ^ KSWZ(row)
  int srow[4], scb[4];
#pragma unroll
  for (int j = 0; j < 4; ++j) {
    const int p = j * 128 + wave * 64 + lane;
    srow[j] = p >> 3;
    scb[j]  = (p & 7) ^ KSWZ(srow[j]);
  }
  const int swl = KSWZ(l15);
  const int esw = 2 * (l15 & 7);                     // P-row 8B-unit swizzle (even -> pairs kept)
  u16* plw = PL[wave];

#define STAGE(buf, s0)                                                              \
  do {                                                                              \
    _Pragma("unroll")                                                               \
    for (int j = 0; j < 4; ++j)                                                     \
      gl_lds16(Kh + (size_t)((s0) + srow[j]) * CH + scb[j] * 8,                     \
               &KB[buf][(j * 128 + wave * 64) * 8]);                                \
    _Pragma("unroll")                                                               \
    for (int j = 0; j < 4; ++j)                                                     \
      gl_lds16(Vh + (size_t)srow[j] * T + (s0) + scb[j] * 8,                        \
               &VB[buf][(j * 128 + wave * 64) * 8]);                                \
  } while (0)

  STAGE(0, 0);

  for (int it = 0; it < NIT; ++it) {
    const int cur = it & 1;
    __syncthreads();                                   // tile[cur] staged & visible
    if (it + 1 < NIT) STAGE(cur ^ 1, (it + 1) * BN);   // async prefetch into idle buf

    const u16* kb = KB[cur];
    const u16* vb = VB[cur];

    // K frags once, reused by 4 tq
    short8 kf[4][2];
#pragma unroll
    for (int nt = 0; nt < 4; ++nt) {
      const int ph0 = quad ^ swl ^ ((nt & 1) * 4);
      const int base = (nt * 16 + l15) * CH;
      kf[nt][0] = *(const short8*)(kb + base + ph0 * 8);
      kf[nt][1] = *(const short8*)(kb + base + (ph0 ^ 4) * 8);
    }

    // per tq: S^T = K Q^T, softmax, packed P write (limits sacc liveness)
#pragma unroll
    for (int tq = 0; tq < 4; ++tq) {
      floatx4 sacc[4];
#pragma unroll
      for (int nt = 0; nt < 4; ++nt) {
        floatx4 z = {0.f, 0.f, 0.f, 0.f};
        z = __builtin_amdgcn_mfma_f32_16x16x32_bf16(kf[nt][0], qf[tq][0], z, 0, 0, 0);
        z = __builtin_amdgcn_mfma_f32_16x16x32_bf16(kf[nt][1], qf[tq][1], z, 0, 0, 0);
        sacc[nt] = z;
      }
      const int tl = tq * 16 + l15;                    // wave-local row
#pragma unroll
      for (int nt = 0; nt < 4; ++nt) {
        floatx4 sv = sacc[nt];
        float p0 = __builtin_amdgcn_exp2f(sv[0]);
        float p1 = __builtin_amdgcn_exp2f(sv[1]);
        float p2 = __builtin_amdgcn_exp2f(sv[2]);
        float p3 = __builtin_amdgcn_exp2f(sv[3]);
        lsum[tq] += (p0 + p1) + (p2 + p3);
        const int phu = (nt * 4 + quad) ^ esw;         // 8B-unit swizzle in row
        uint2 w; w.x = pk2(p0, p1); w.y = pk2(p2, p3);
        *(uint2*)(plw + tl * BN + phu * 4) = w;
      }
    }

    // O = P V^T : A = P (wave-local LDS, swizzled), B = V^T (V [c][s] LDS, swizzled)
#pragma unroll
    for (int ks = 0; ks < 2; ++ks) {
      short8 pf[4];
#pragma unroll
      for (int tq = 0; tq < 4; ++tq) {
        const int phu = (ks * 8 + quad * 2) ^ esw;     // even -> 16B-aligned pair
        pf[tq] = *(const short8*)(plw + (tq * 16 + l15) * BN + phu * 4);
      }
#pragma unroll
      for (int mt = 0; mt < 4; ++mt) {
        const int ph = quad ^ swl ^ ((mt & 1) * 4) ^ (ks * 4);
        const short8 vf = *(const short8*)(vb + (mt * 16 + l15) * BN + ph * 8);
#pragma unroll
        for (int tq = 0; tq < 4; ++tq)
          oacc[tq][mt] = __builtin_amdgcn_mfma_f32_16x16x32_bf16(pf[tq], vf, oacc[tq][mt], 0, 0, 0);
      }
    }
  }

  // epilogue: reduce row sums across quads; per-output-row linv via shfl
  float ls[4];
#pragma unroll
  for (int tq = 0; tq < 4; ++tq) {
    float s = lsum[tq];
    s += __shfl_xor(s, 16, 64);
    s += __shfl_xor(s, 32, 64);
    ls[tq] = s;                                        // full sum for row tq*16 + l15
  }
  float linv[4][4];
#pragma unroll
  for (int tq = 0; tq < 4; ++tq)
#pragma unroll
    for (int r = 0; r < 4; ++r)
      linv[tq][r] = 1.0f / __shfl(ls[tq], quad * 4 + r, 64);

  // O rows t = t0w + tq*16 + quad*4 + r ; cols c = mt*16 + l15 ; float4 over r
#pragma unroll
  for (int tq = 0; tq < 4; ++tq) {
    const int tg = t0w + tq * 16 + quad * 4;
    const int band = tg >> 10, tt = tg & 1023;
    float* obase = out + (size_t)band * (4 * 512 * 1024)
                       + (size_t)b * (512 * 1024)
                       + (size_t)(h * CH) * 1024 + tt;
#pragma unroll
    for (int mt = 0; mt < 4; ++mt) {
      const int c = mt * 16 + l15;
      float4 v;
      v.x = oacc[tq][mt][0] * linv[tq][0];
      v.y = oacc[tq][mt][1] * linv[tq][1];
      v.z = oacc[tq][mt][2] * linv[tq][2];
      v.w = oacc[tq][mt][3] * linv[tq][3];
      *(float4*)(obase + (size_t)c * 1024) = v;
    }
  }
}

extern "C" void kernel_launch(void* const* d_in, const int* in_sizes, int n_in,
                              void* d_out, int out_size, void* d_ws, size_t ws_size,
                              hipStream_t stream) {
  (void)in_sizes; (void)n_in; (void)out_size; (void)ws_size;
  const float* qkv = (const float*)d_in[0];
  u16* Kt = (u16*)d_ws;                                 // 12.6 MB bf16
  u16* Vo = Kt + (size_t)HEADS * T * CH;                // 12.6 MB bf16
  float* out = (float*)d_out;

  prep<<<dim3(48, HEADS, 2), 256, 0, stream>>>(qkv, Kt, Vo);
  attn<<<dim3(T / BM, HEADS), 128, 0, stream>>>(qkv, Kt, Vo, out);
}